// Round 12
// baseline (119.078 us; speedup 1.0000x reference)
//
#include <hip/hip_runtime.h>
#include <hip/hip_bf16.h>
#include <stdint.h>

typedef __attribute__((ext_vector_type(8))) __bf16 bf16x8;
typedef __attribute__((ext_vector_type(4))) float f32x4;
typedef unsigned short u16;

__device__ __forceinline__ u16 f2bf(float f) {
  unsigned u = __builtin_bit_cast(unsigned, f);
  unsigned r = 0x7FFFu + ((u >> 16) & 1u);
  return (u16)((u + r) >> 16);
}

__device__ __forceinline__ __bf16 f2bf_v(float f) {
  __hip_bfloat16 h = __float2bfloat16(f);
  return __builtin_bit_cast(__bf16, h);
}

__device__ __forceinline__ void gload16(const void* g, void* l) {
  __builtin_amdgcn_global_load_lds(
      (__attribute__((address_space(1))) void*)(g),
      (__attribute__((address_space(3))) void*)(l),
      16, 0, 0);
}

// ---- deg / rsqrt -----------------------------------------------------------
__global__ void row_deg_k(const float* __restrict__ adj, float* __restrict__ dis, int N) {
  int row = blockIdx.x;
  const float4* a = (const float4*)(adj + (size_t)row * N);
  float s = 0.f;
  for (int j = threadIdx.x; j < N / 4; j += 256) {
    float4 v = a[j];
    s += v.x + v.y + v.z + v.w;
  }
#pragma unroll
  for (int off = 32; off > 0; off >>= 1) s += __shfl_down(s, off, 64);
  __shared__ float wsum[4];
  if ((threadIdx.x & 63) == 0) wsum[threadIdx.x >> 6] = s;
  __syncthreads();
  if (threadIdx.x == 0) {
    float t = wsum[0] + wsum[1] + wsum[2] + wsum[3];
    dis[row] = (t > 0.f) ? (1.0f / sqrtf(t)) : 0.f;
  }
}

// ---- W [512,512] -> W^T bf16 ----------------------------------------------
__global__ void conv_wt_k(const float* __restrict__ w, u16* __restrict__ wt) {
  int idx = blockIdx.x * 256 + threadIdx.x;  // 262144 total
  int i = idx >> 9, o = idx & 511;
  wt[o * 512 + i] = f2bf(w[idx]);
}

// ---- norm_adj bf16 ---------------------------------------------------------
__global__ void make_nadj_k(const float* __restrict__ adj, const float* __restrict__ dis,
                            u16* __restrict__ o, int N) {
  int idx = blockIdx.x * 256 + threadIdx.x;  // per float4, N*N/4 total
  int i = idx >> 9;                          // N/4 = 512 float4 per row
  int j4 = (idx & 511) * 4;
  float di = dis[i];
  float4 a = ((const float4*)adj)[idx];
  ushort4 u;
  u.x = f2bf(a.x * di * dis[j4 + 0]);
  u.y = f2bf(a.y * di * dis[j4 + 1]);
  u.z = f2bf(a.z * di * dis[j4 + 2]);
  u.w = f2bf(a.w * di * dis[j4 + 3]);
  ((ushort4*)o)[idx] = u;
}

// ---- GEMM1b: Ct = (X @ Wt^T)^T, 128x256 tile, BK=32 dbuf, 2 blocks/CU ------
// X fp32 [M,512]; Wt bf16 [512,512]; Ct bf16 [512][M]. 512 thr (8 waves 2Mx4N,
// wave 64x64). LDS 48 KiB: A[2][128][32]bf16 @0, B[2][256][32] @8192(elem).
// BK=32 (64B rows) swizzle: elem ^= ((row>>1)&3)<<3 (uniform 8 lanes/granule
// for reads AND the A-side ds_write). A: reg-staged fp32 issue-early + cvt +
// swizzled ds_write after MFMAs (T14). B: gload_lds, pre-swizzled source,
// linear dest. 1 syncthreads/tile (drains stage vm + read lgkm).
__launch_bounds__(512, 4)
__global__ void gemm1b_k(const float* __restrict__ X,
                         const u16* __restrict__ Wt,
                         u16* __restrict__ Ct, int M) {
  __shared__ __align__(16) u16 lds[24576];

  const int tid = threadIdx.x;
  const int lane = tid & 63;
  const int wid = tid >> 6;
  const int wr = wid >> 2;
  const int wc = wid & 3;

  // XCD swizzle; n-pair of one m-tile adjacent (same XCD chunk) for X reuse
  const int flat = blockIdx.x;
  const int wg = (flat & 7) * 64 + (flat >> 3);   // grid 512
  const int m_t = wg >> 1;
  const int n_t = wg & 1;
  const int rowBase = m_t * 128;
  const int colBase = n_t * 256;

  // A staging (reg path): row = tid>>2 (0..127), 8 floats at (tid&3)*8
  const int rowA = tid >> 2;
  const int qA = (tid & 3) * 8;
  const int swzA = ((rowA >> 1) & 3) << 3;
  const float* gX = X + (size_t)(rowBase + rowA) * 512 + qA;
  u16* lA = lds + rowA * 32 + (qA ^ swzA);

  // B staging (DMA): row = tid>>2 (+0/+128), kk=(tid&3)*8; dest linear
  const int kkB = (tid & 3) * 8;
  const int swzB = ((rowA >> 1) & 3) << 3;   // rows r and r+128: same (row>>1)&3
  const u16* gB = Wt + (size_t)(colBase + rowA) * 512 + (kkB ^ swzB);
  u16* lBd = lds + 8192 + rowA * 32 + kkB;   // = 8192 + tid*8 (lane-linear)

  // fragment reads
  const int fr = lane & 15;
  const int rsw = ((fr >> 1) & 3) << 3;
  const int kp = ((lane >> 4) * 8) ^ rsw;
  const u16* fA = lds + (wr * 64 + fr) * 32;
  const u16* fB = lds + 8192 + (wc * 64 + fr) * 32;

  f32x4 acc[4][4] = {};
  f32x4 xv0, xv1;

  const int NT = 16;  // K=512, BK=32

  // prologue: tile 0 -> buf 0
  xv0 = *(const f32x4*)(gX);
  xv1 = *(const f32x4*)(gX + 4);
  {
    bf16x8 v;
#pragma unroll
    for (int i = 0; i < 4; ++i) { v[i] = f2bf_v(xv0[i]); v[4 + i] = f2bf_v(xv1[i]); }
    *(bf16x8*)(lA) = v;
  }
  gload16(gB, lBd);
  gload16(gB + (size_t)128 * 512, lBd + 4096);
  __syncthreads();

  for (int t = 0; t < NT; ++t) {
    const int c = t & 1;
    const int cn = c ^ 1;
    const int tn = (t + 1 < NT) ? t + 1 : NT - 1;  // clamp: staged, never read

    // issue-early: next tile's X loads + B stages
    xv0 = *(const f32x4*)(gX + tn * 32);
    xv1 = *(const f32x4*)(gX + tn * 32 + 4);
    gload16(gB + tn * 32, lBd + cn * 8192);
    gload16(gB + (size_t)128 * 512 + tn * 32, lBd + cn * 8192 + 4096);

    // compute tile t from buf c
    bf16x8 a[4], bb[4];
#pragma unroll
    for (int m = 0; m < 4; ++m) a[m] = *(const bf16x8*)(fA + c * 4096 + m * 512 + kp);
#pragma unroll
    for (int n = 0; n < 4; ++n) bb[n] = *(const bf16x8*)(fB + c * 8192 + n * 512 + kp);
#pragma unroll
    for (int m = 0; m < 4; ++m)
#pragma unroll
      for (int n = 0; n < 4; ++n)
        acc[m][n] = __builtin_amdgcn_mfma_f32_16x16x32_bf16(a[m], bb[n], acc[m][n], 0, 0, 0);

    // write-late: cvt + swizzled ds_write of next A tile into buf cn
    {
      bf16x8 v;
#pragma unroll
      for (int i = 0; i < 4; ++i) { v[i] = f2bf_v(xv0[i]); v[4 + i] = f2bf_v(xv1[i]); }
      *(bf16x8*)(lA + cn * 4096) = v;
    }
    __syncthreads();
  }

  // epilogue: bf16 C^T write
#pragma unroll
  for (int m = 0; m < 4; ++m) {
    const int r = rowBase + wr * 64 + m * 16 + (lane >> 4) * 4;
#pragma unroll
    for (int n = 0; n < 4; ++n) {
      const int cc = colBase + wc * 64 + n * 16 + fr;
      ushort4 v;
      v.x = f2bf(acc[m][n][0]);
      v.y = f2bf(acc[m][n][1]);
      v.z = f2bf(acc[m][n][2]);
      v.w = f2bf(acc[m][n][3]);
      *reinterpret_cast<ushort4*>(&Ct[(size_t)cc * M + r]) = v;
    }
  }
}

// ---- GEMM2c: 128x256 tile, BK=32 double-buffered, 2 blocks/CU --------------
// C = A[M,K] * Bt[N,K]^T, f32 out + bias. LDS 48 KiB: A[2][128][32] @0,
// B[2][256][32] @8192. Stage t+1 at top of iter t (latency hides under
// reads+MFMA); 1 syncthreads/tile. Swizzle elem ^= ((row>>1)&3)<<3.
__launch_bounds__(512, 4)
__global__ void gemm2c_k(const u16* __restrict__ A, int lda,
                         const u16* __restrict__ Bt, int ldb,
                         float* __restrict__ C, int ldc,
                         const float* __restrict__ bias, int K,
                         int nMT, int nNT, size_t zBt, size_t zC) {
  __shared__ __align__(16) u16 lds[24576];

  const int tid = threadIdx.x;
  const int lane = tid & 63;
  const int wid = tid >> 6;
  const int wr = wid >> 2;
  const int wc = wid & 3;

  const int flat = blockIdx.x;
  const int cpx = (int)gridDim.x >> 3;
  const int wg = (flat & 7) * cpx + (flat >> 3);
  const int m_t = wg % nMT;
  const int rest = wg / nMT;
  const int n_t = rest % nNT;
  const int b = rest / nNT;
  const int rowBase = m_t * 128;
  const int colBase = n_t * 256;
  const u16* Bb = Bt + (size_t)b * zBt;

  // staging: row = tid>>2 (0..127), kk = (tid&3)*8; pre-swizzled source
  const int rA = tid >> 2;
  const int kk = (tid & 3) * 8;
  const int swz = ((rA >> 1) & 3) << 3;       // rows r and r+128 share swz
  const u16* gA = A + (size_t)(rowBase + rA) * lda + (kk ^ swz);
  const u16* gB = Bb + (size_t)(colBase + rA) * ldb + (kk ^ swz);
  u16* lAd = lds + rA * 32 + kk;              // = tid*8 (lane-linear)
  u16* lBd = lds + 8192 + rA * 32 + kk;

  // fragment reads
  const int fr = lane & 15;
  const int rsw = ((fr >> 1) & 3) << 3;
  const int kp = ((lane >> 4) * 8) ^ rsw;
  const u16* fA = lds + (wr * 64 + fr) * 32;
  const u16* fB = lds + 8192 + (wc * 64 + fr) * 32;

  f32x4 acc[4][4] = {};
  const int NT = K >> 5;

  // prologue: tile 0 -> buf 0
  gload16(gA, lAd);
  gload16(gB, lBd);
  gload16(gB + (size_t)128 * ldb, lBd + 4096);
  __syncthreads();

  for (int t = 0; t < NT; ++t) {
    const int c = t & 1;
    const int cn = c ^ 1;
    const int tn = (t + 1 < NT) ? t + 1 : NT - 1;

    // issue-early stage of tile t+1 into buf cn
    gload16(gA + tn * 32, lAd + cn * 4096);
    gload16(gB + tn * 32, lBd + cn * 8192);
    gload16(gB + (size_t)128 * ldb + tn * 32, lBd + cn * 8192 + 4096);

    // compute tile t from buf c
    bf16x8 a[4], bb[4];
#pragma unroll
    for (int m = 0; m < 4; ++m) a[m] = *(const bf16x8*)(fA + c * 4096 + m * 512 + kp);
#pragma unroll
    for (int n = 0; n < 4; ++n) bb[n] = *(const bf16x8*)(fB + c * 8192 + n * 512 + kp);
#pragma unroll
    for (int m = 0; m < 4; ++m)
#pragma unroll
      for (int n = 0; n < 4; ++n)
        acc[m][n] = __builtin_amdgcn_mfma_f32_16x16x32_bf16(a[m], bb[n], acc[m][n], 0, 0, 0);

    __syncthreads();  // drains stage vm (t+1 ready) + read lgkm (buf c free)
  }

  // epilogue: f32 C + bias
  float* Cb = C + (size_t)b * zC;
#pragma unroll
  for (int n = 0; n < 4; ++n) {
    const int cc = colBase + wc * 64 + n * 16 + fr;
    const float bv = bias[cc];
#pragma unroll
    for (int m = 0; m < 4; ++m) {
      const int r = rowBase + wr * 64 + m * 16 + (lane >> 4) * 4;
#pragma unroll
      for (int j = 0; j < 4; ++j)
        Cb[(size_t)(r + j) * ldc + cc] = acc[m][n][j] + bv;
    }
  }
}

extern "C" void kernel_launch(void* const* d_in, const int* in_sizes, int n_in,
                              void* d_out, int out_size, void* d_ws, size_t ws_size,
                              hipStream_t stream) {
  const int B = 16, N = 2048, FIN = 512, FOUT = 512;
  const float* x    = (const float*)d_in[0];
  const float* adj  = (const float*)d_in[1];
  const float* w    = (const float*)d_in[2];
  const float* bias = (const float*)d_in[3];
  float* out = (float*)d_out;
  char* ws = (char*)d_ws;

  float* dis = (float*)ws;                       // 8 KB
  u16* wt    = (u16*)(ws + 8192);                // 512 KB  W^T [FOUT][FIN]
  u16* nadj  = (u16*)(ws + 532480);              // 8 MB    [N][N]
  u16* st    = (u16*)(ws + 8921088);             // 32 MB   support^T [FOUT][B*N]

  row_deg_k<<<N, 256, 0, stream>>>(adj, dis, N);
  conv_wt_k<<<(FIN * FOUT) / 256, 256, 0, stream>>>(w, wt);
  make_nadj_k<<<(N * N / 4) / 256, 256, 0, stream>>>(adj, dis, nadj, N);

  // GEMM1b: st = (x @ wt^T)^T ; grid 256*2 = 512 blocks (2/CU)
  gemm1b_k<<<dim3(512), 512, 0, stream>>>(x, wt, st, B * N);

  // GEMM2c: out[b] = nadj @ support[b] + bias ; grid 16*2*16 = 512 blocks (2/CU)
  gemm2c_k<<<dim3(512), 512, 0, stream>>>(
      nadj, N, st, B * N, out, FOUT, bias, N, 16, 2,
      (size_t)N, (size_t)N * FOUT);
}